// Round 10
// baseline (371.827 us; speedup 1.0000x reference)
//
#include <hip/hip_runtime.h>
#include <hip/hip_bf16.h>
#include <math.h>

#define S 2048
#define DM 2048
#define NH 16
#define DH 128
#define DR 64
#define DKV 512
#define DQ 1024
#define DQK 192  // DH + DR
#define QSCALE 0.07216878364870323f  // 1/sqrt(192)

typedef __bf16 bf16x8 __attribute__((ext_vector_type(8)));
typedef float f32x4 __attribute__((ext_vector_type(4)));
typedef unsigned short u16;

__device__ inline unsigned int pack2_bf16(float a, float b) {
    __hip_bfloat16 ha = __float2bfloat16(a);
    __hip_bfloat16 hb = __float2bfloat16(b);
    unsigned short ua = *reinterpret_cast<unsigned short*>(&ha);
    unsigned short ub = *reinterpret_cast<unsigned short*>(&hb);
    return (unsigned int)ua | ((unsigned int)ub << 16);
}
__device__ inline u16 f2bf(float v) {
    __hip_bfloat16 hb = __float2bfloat16(v);
    return *reinterpret_cast<u16*>(&hb);
}
__device__ inline void gload_lds16(const void* g, void* l) {
    __builtin_amdgcn_global_load_lds(
        (const __attribute__((address_space(1))) void*)g,
        (__attribute__((address_space(3))) void*)l, 16, 0, 0);
}

// ---------------- RoPE cos/sin table ----------------
__global__ void rope_table_kernel(float* __restrict__ cosT, float* __restrict__ sinT) {
    int idx = blockIdx.x * blockDim.x + threadIdx.x;
    if (idx >= S * (DR / 2)) return;
    int pos = idx / (DR / 2);
    int j   = idx % (DR / 2);
    float inv = __expf(-((float)(2 * j) / (float)DR) * logf(10000.0f));
    float ang = (float)pos * inv;
    cosT[idx] = cosf(ang);
    sinT[idx] = sinf(ang);
}

// ---------------- f32 -> bf16 elementwise (x) ----------------
__global__ void convert_bf16_kernel(const float* __restrict__ in, u16* __restrict__ outp, int n4) {
    int idx = blockIdx.x * blockDim.x + threadIdx.x;
    if (idx >= n4) return;
    float4 v = *reinterpret_cast<const float4*>(&in[(size_t)idx * 4]);
    uint2 w;
    w.x = pack2_bf16(v.x, v.y);
    w.y = pack2_bf16(v.z, v.w);
    *reinterpret_cast<uint2*>(&outp[(size_t)idx * 4]) = w;
}

// ---------------- fused transpose-convert for all 8 weights ----------------
__global__ __launch_bounds__(256) void wt_all_kernel(
    const float* __restrict__ W0, const float* __restrict__ W1, const float* __restrict__ W2,
    const float* __restrict__ W3, const float* __restrict__ W4, const float* __restrict__ W5,
    const float* __restrict__ W6, const float* __restrict__ W7,
    u16* __restrict__ D0, u16* __restrict__ D1, u16* __restrict__ D2, u16* __restrict__ D3,
    u16* __restrict__ D4, u16* __restrict__ D5, u16* __restrict__ D6, u16* __restrict__ D7) {
    __shared__ u16 tile[64][65];
    const float* W; u16* D; int N, K, local;
    int bnum = blockIdx.x;
    if (bnum < 256)       { W = W0; D = D0; N = 512;  K = 2048; local = bnum; }
    else if (bnum < 768)  { W = W1; D = D1; N = 1024; K = 2048; local = bnum - 256; }
    else if (bnum < 1280) { W = W2; D = D2; N = 1024; K = 2048; local = bnum - 768; }
    else if (bnum < 1536) { W = W3; D = D3; N = 2048; K = 512;  local = bnum - 1280; }
    else if (bnum < 1792) { W = W4; D = D4; N = 2048; K = 512;  local = bnum - 1536; }
    else if (bnum < 2304) { W = W5; D = D5; N = 2048; K = 1024; local = bnum - 1792; }
    else if (bnum < 2560) { W = W6; D = D6; N = 1024; K = 1024; local = bnum - 2304; }
    else                  { W = W7; D = D7; N = 2048; K = 2048; local = bnum - 2560; }
    const int nt = N / 64;
    const int n0 = (local % nt) * 64;
    const int k0 = (local / nt) * 64;
    const int tx = threadIdx.x & 15;
    const int ty = threadIdx.x >> 4;
#pragma unroll
    for (int rep = 0; rep < 4; ++rep) {
        int kk = rep * 16 + ty;
        float4 v = *reinterpret_cast<const float4*>(&W[(size_t)(k0 + kk) * N + n0 + tx * 4]);
        tile[kk][tx * 4 + 0] = f2bf(v.x);
        tile[kk][tx * 4 + 1] = f2bf(v.y);
        tile[kk][tx * 4 + 2] = f2bf(v.z);
        tile[kk][tx * 4 + 3] = f2bf(v.w);
    }
    __syncthreads();
#pragma unroll
    for (int rep = 0; rep < 4; ++rep) {
        int nn = rep * 16 + ty;
        uint2 w;
        w.x = (unsigned int)tile[tx * 4 + 0][nn] | ((unsigned int)tile[tx * 4 + 1][nn] << 16);
        w.y = (unsigned int)tile[tx * 4 + 2][nn] | ((unsigned int)tile[tx * 4 + 3][nn] << 16);
        *reinterpret_cast<uint2*>(&D[(size_t)(n0 + nn) * K + k0 + tx * 4]) = w;
    }
}

// ---------------- bf16 MFMA GEMM with fused epilogues (R8-verified) ----------------
template <int MODE>
__global__ __launch_bounds__(256) void gemm_fused_kernel(
    const u16* __restrict__ A, const u16* __restrict__ BT,
    void* __restrict__ P0v, void* __restrict__ P1v, void* __restrict__ P2v,
    const float* __restrict__ cosT, const float* __restrict__ sinT, int K) {
    __shared__ u16 lds[2][6144];
    const int tid  = threadIdx.x;
    const int wave = tid >> 6;
    const int lane = tid & 63;
    const int c16  = lane & 15;
    const int g    = lane >> 4;
    const int bm = blockIdx.y * 64;
    const int bn = blockIdx.x * 128;
    const int wm = (wave >> 1) * 32;
    const int wn = (wave & 1) * 64;

    f32x4 acc[2][4];
#pragma unroll
    for (int i = 0; i < 2; ++i)
#pragma unroll
        for (int j = 0; j < 4; ++j) acc[i][j] = f32x4{0.f, 0.f, 0.f, 0.f};

    auto stage = [&](int buf, int k0) {
        {
            int L = tid;
            int rp = L >> 3, e = L & 7, x = e ^ (rp & 7);
            int row = 2 * rp + (x >> 2), kc = x & 3;
            gload_lds16(A + (size_t)(bm + row) * K + k0 + kc * 8, &lds[buf][wave * 512]);
        }
#pragma unroll
        for (int r = 0; r < 2; ++r) {
            int L = r * 256 + tid;
            int rp = L >> 3, e = L & 7, x = e ^ (rp & 7);
            int row = 2 * rp + (x >> 2), kc = x & 3;
            gload_lds16(BT + (size_t)(bn + row) * K + k0 + kc * 8,
                        &lds[buf][2048 + (r * 256 + wave * 64) * 8]);
        }
    };

    const int NT = K / 32;
    stage(0, 0);
    __syncthreads();
    int cur = 0;
    for (int t = 0; t < NT; ++t) {
        if (t + 1 < NT) stage(cur ^ 1, (t + 1) * 32);
        bf16x8 af[2], bfr[4];
#pragma unroll
        for (int i = 0; i < 2; ++i) {
            int row  = wm + i * 16 + c16;
            int slot = ((row >> 1) << 3) + ((((row & 1) << 2) + g) ^ ((row >> 1) & 7));
            af[i] = *reinterpret_cast<const bf16x8*>(&lds[cur][slot * 8]);
        }
#pragma unroll
        for (int j = 0; j < 4; ++j) {
            int row  = wn + j * 16 + c16;
            int slot = ((row >> 1) << 3) + ((((row & 1) << 2) + g) ^ ((row >> 1) & 7));
            bfr[j] = *reinterpret_cast<const bf16x8*>(&lds[cur][2048 + slot * 8]);
        }
#pragma unroll
        for (int i = 0; i < 2; ++i)
#pragma unroll
            for (int j = 0; j < 4; ++j)
                acc[i][j] = __builtin_amdgcn_mfma_f32_16x16x32_bf16(af[i], bfr[j], acc[i][j], 0, 0, 0);
        __syncthreads();
        cur ^= 1;
    }

#pragma unroll
    for (int i = 0; i < 2; ++i)
#pragma unroll
        for (int j = 0; j < 4; ++j) {
            const int mrow = bm + wm + i * 16 + g * 4;
            const int col  = bn + wn + j * 16 + c16;
            if constexpr (MODE == 0) {
                if (col < 512) {
                    u16* down_kv = (u16*)P0v;
#pragma unroll
                    for (int r = 0; r < 4; ++r)
                        down_kv[(size_t)(mrow + r) * DKV + col] = f2bf(acc[i][j][r]);
                } else if (col < 1536) {
                    u16* down_q = (u16*)P1v;
#pragma unroll
                    for (int r = 0; r < 4; ++r)
                        down_q[(size_t)(mrow + r) * DQ + (col - 512)] = f2bf(acc[i][j][r]);
                } else {
                    u16* k_asm = (u16*)P2v;
                    const int cc = col - 1536, h = cc >> 6, rr = cc & 63, jj = rr >> 1;
#pragma unroll
                    for (int r = 0; r < 4; ++r) {
                        int pos = mrow + r;
                        float self = acc[i][j][r];
                        float vp   = __shfl_xor(self, 1);
                        float c = cosT[pos * (DR / 2) + jj];
                        float s = sinT[pos * (DR / 2) + jj];
                        float val = (rr & 1) ? (vp * s + self * c) : (self * c - vp * s);
                        k_asm[((size_t)h * S + pos) * DQK + DH + rr] = f2bf(val);
                    }
                }
            } else if constexpr (MODE == 1) {
                if (col < 2048) {
                    u16* k_asm = (u16*)P0v;
                    const int h = col >> 7, d = col & 127;
#pragma unroll
                    for (int r = 0; r < 4; ++r)
                        k_asm[((size_t)h * S + mrow + r) * DQK + d] = f2bf(acc[i][j][r]);
                } else {
                    u16* vt = (u16*)P1v;
                    const int cc = col - 2048, h = cc >> 7, d = cc & 127;
                    uint2 w;
                    w.x = pack2_bf16(acc[i][j][0], acc[i][j][1]);
                    w.y = pack2_bf16(acc[i][j][2], acc[i][j][3]);
                    *reinterpret_cast<uint2*>(&vt[((size_t)h * DH + d) * S + mrow]) = w;
                }
            } else if constexpr (MODE == 2) {
                u16* q_asm = (u16*)P0v;
                if (col < 2048) {
                    const int h = col >> 7, d = col & 127;
#pragma unroll
                    for (int r = 0; r < 4; ++r)
                        q_asm[((size_t)h * S + mrow + r) * DQK + d] = f2bf(acc[i][j][r] * QSCALE);
                } else {
                    const int cc = col - 2048, h = cc >> 6, rr = cc & 63, jj = rr >> 1;
#pragma unroll
                    for (int r = 0; r < 4; ++r) {
                        int pos = mrow + r;
                        float self = acc[i][j][r];
                        float vp   = __shfl_xor(self, 1);
                        float c = cosT[pos * (DR / 2) + jj];
                        float s = sinT[pos * (DR / 2) + jj];
                        float val = (rr & 1) ? (vp * s + self * c) : (self * c - vp * s);
                        q_asm[((size_t)h * S + pos) * DQK + DH + rr] = f2bf(val * QSCALE);
                    }
                }
            } else {  // MODE 3
                float* outp = (float*)P0v;
#pragma unroll
                for (int r = 0; r < 4; ++r)
                    outp[(size_t)(mrow + r) * DM + col] = acc[i][j][r];
            }
        }
}

// ---------------- MFMA flash attention v7: independent waves, reg-prefetched K/V ----------------
// 512 blocks x 4 INDEPENDENT waves (no __syncthreads). Each wave owns 16 q-rows.
// K of tile t+1 prefetched into alternate named register set (parity-unrolled);
// V of tile t issued at tile start (covered by QK^T+softmax). P via wave-private
// conflict-free LDS (R6-verified map). XCD head-pinning + big/small interleave.
__global__ __launch_bounds__(256) void attn_mfma_kernel(const u16* __restrict__ q,   // (NH,S,192) pre-scaled
                                                        const u16* __restrict__ k,   // (NH,S,192)
                                                        const u16* __restrict__ vt,  // (NH,DH,S)
                                                        u16* __restrict__ outp) {    // (S, NH*DH) bf16
    const int wgid = blockIdx.x;
    const int xcd  = wgid & 7;
    const int i    = wgid >> 3;  // 0..63 per xcd
    const int h  = (i < 32) ? (xcd * 2) : (xcd * 2 + 1);
    const int qt = (i < 32) ? (31 - i) : (i - 32);
    const int q0 = qt * 64;

    const int wave = threadIdx.x >> 6;
    const int lane = threadIdx.x & 63;
    const int col  = lane & 15;
    const int g    = lane >> 4;
    const int qw   = q0 + wave * 16;  // this wave's 16 q-rows (independent)

    __shared__ __align__(16) u16 p_lds[4][512];  // per-wave P, conflict-free map
    const int pv7 = (col >> 1) & 7;
    const int pvb = (col & 1) << 2;

    // Q fragments: lane holds Q[qw+col][g*8+e + 32c]
    bf16x8 qf[6];
    {
        const u16* qbase = q + ((size_t)h * S + qw + col) * DQK + g * 8;
#pragma unroll
        for (int c = 0; c < 6; ++c) qf[c] = *reinterpret_cast<const bf16x8*>(qbase + c * 32);
    }

    const u16* kbase = k + ((size_t)h * S + col) * DQK + g * 8;       // + row*DQK
    const u16* vbase = vt + ((size_t)h * DH + col) * S + g * 8;       // + 16c*S + j0

    f32x4 acc[8];
#pragma unroll
    for (int c = 0; c < 8; ++c) acc[c] = f32x4{0.f, 0.f, 0.f, 0.f};
    float m_run = -1e30f, l_run = 0.f;

    const int kend = qw + 16;
    const int T    = (kend + 31) / 32;  // per-wave trip count (waves diverge freely)

    bf16x8 kfA[12], kfB[12], vfc[8];

    // issue K loads for a 32-key tile into a named set (12 x 16B, batched in flight)
    auto issueK = [&](bf16x8 (&kf)[12], int j0) {
        const u16* kb = kbase + (size_t)j0 * DQK;
#pragma unroll
        for (int tt = 0; tt < 2; ++tt)
#pragma unroll
            for (int c = 0; c < 6; ++c)
                kf[tt * 6 + c] = *reinterpret_cast<const bf16x8*>(kb + (size_t)tt * 16 * DQK + c * 32);
    };

    // one 32-key tile: V issue at start; QK^T (split chains); mask; softmax; P->LDS; PV
    auto body = [&](bf16x8 (&kc)[12], int t) {
        const int j0 = t * 32;
        // V for THIS tile: in flight during QK^T + softmax
        const u16* vb = vbase + j0;
#pragma unroll
        for (int c = 0; c < 8; ++c)
            vfc[c] = *reinterpret_cast<const bf16x8*>(vb + (size_t)c * 16 * S);

        // QK^T, two half-chains per 16-key sub-tile to halve MFMA dep chain
        f32x4 s0a = f32x4{0.f, 0.f, 0.f, 0.f}, s0b = f32x4{0.f, 0.f, 0.f, 0.f};
        f32x4 s1a = f32x4{0.f, 0.f, 0.f, 0.f}, s1b = f32x4{0.f, 0.f, 0.f, 0.f};
        s0a = __builtin_amdgcn_mfma_f32_16x16x32_bf16(kc[0], qf[0], s0a, 0, 0, 0);
        s0b = __builtin_amdgcn_mfma_f32_16x16x32_bf16(kc[1], qf[1], s0b, 0, 0, 0);
        s0a = __builtin_amdgcn_mfma_f32_16x16x32_bf16(kc[2], qf[2], s0a, 0, 0, 0);
        s0b = __builtin_amdgcn_mfma_f32_16x16x32_bf16(kc[3], qf[3], s0b, 0, 0, 0);
        s0a = __builtin_amdgcn_mfma_f32_16x16x32_bf16(kc[4], qf[4], s0a, 0, 0, 0);
        s0b = __builtin_amdgcn_mfma_f32_16x16x32_bf16(kc[5], qf[5], s0b, 0, 0, 0);
        s1a = __builtin_amdgcn_mfma_f32_16x16x32_bf16(kc[6], qf[0], s1a, 0, 0, 0);
        s1b = __builtin_amdgcn_mfma_f32_16x16x32_bf16(kc[7], qf[1], s1b, 0, 0, 0);
        s1a = __builtin_amdgcn_mfma_f32_16x16x32_bf16(kc[8], qf[2], s1a, 0, 0, 0);
        s1b = __builtin_amdgcn_mfma_f32_16x16x32_bf16(kc[9], qf[3], s1b, 0, 0, 0);
        s1a = __builtin_amdgcn_mfma_f32_16x16x32_bf16(kc[10], qf[4], s1a, 0, 0, 0);
        s1b = __builtin_amdgcn_mfma_f32_16x16x32_bf16(kc[11], qf[5], s1b, 0, 0, 0);
        f32x4 st[2];
        st[0] = s0a + s0b;
        st[1] = s1a + s1b;

        // causal mask (q = qw+col, key = j0+16tt+4g+r)
#pragma unroll
        for (int tt = 0; tt < 2; ++tt) {
            if (j0 + 16 * tt + 15 > qw) {
#pragma unroll
                for (int r = 0; r < 4; ++r) {
                    int key = j0 + 16 * tt + 4 * g + r;
                    st[tt][r] = (key > qw + col) ? -1e30f : st[tt][r];
                }
            }
        }
        // online softmax with defer-max
        float tmax = fmaxf(fmaxf(fmaxf(st[0][0], st[0][1]), fmaxf(st[0][2], st[0][3])),
                           fmaxf(fmaxf(st[1][0], st[1][1]), fmaxf(st[1][2], st[1][3])));
        tmax = fmaxf(tmax, __shfl_xor(tmax, 16));
        tmax = fmaxf(tmax, __shfl_xor(tmax, 32));
        float m_new;
        if (__all(tmax - m_run <= 8.0f)) {
            m_new = m_run;
        } else {
            m_new = fmaxf(m_run, tmax);
            float r_scale = __expf(m_run - m_new);
            l_run *= r_scale;
#pragma unroll
            for (int c = 0; c < 8; ++c) {
                acc[c][0] *= r_scale; acc[c][1] *= r_scale;
                acc[c][2] *= r_scale; acc[c][3] *= r_scale;
            }
            m_run = m_new;
        }
        float p[8];
        float psum = 0.f;
#pragma unroll
        for (int tt = 0; tt < 2; ++tt)
#pragma unroll
            for (int r = 0; r < 4; ++r) {
                float pv = __expf(st[tt][r] - m_new);
                p[tt * 4 + r] = pv;
                psum += pv;
            }
        psum += __shfl_xor(psum, 16);
        psum += __shfl_xor(psum, 32);
        l_run += psum;
        // P -> p_lds (wave-private; lgkmcnt ordering only, no barrier)
#pragma unroll
        for (int tt = 0; tt < 2; ++tt) {
            uint2 w;
            w.x = pack2_bf16(p[tt * 4 + 0], p[tt * 4 + 1]);
            w.y = pack2_bf16(p[tt * 4 + 2], p[tt * 4 + 3]);
            int ch   = 2 * tt + (g >> 1);
            int slot = ((col >> 1) << 3) + ((pvb + ch) ^ pv7);
            *reinterpret_cast<uint2*>(&p_lds[wave][slot * 8 + (g & 1) * 4]) = w;
        }
        {
            int slot = ((col >> 1) << 3) + ((pvb + g) ^ pv7);
            bf16x8 pf = *reinterpret_cast<const bf16x8*>(&p_lds[wave][slot * 8]);
#pragma unroll
            for (int c = 0; c < 8; ++c)
                acc[c] = __builtin_amdgcn_mfma_f32_16x16x32_bf16(vfc[c], pf, acc[c], 0, 0, 0);
        }
    };

    issueK(kfA, 0);
    for (int t = 0; t < T; ++t) {
        if ((t & 1) == 0) {
            if (t + 1 < T) issueK(kfB, (t + 1) * 32);  // in flight during body(kfA)
            body(kfA, t);
        } else {
            if (t + 1 < T) issueK(kfA, (t + 1) * 32);
            body(kfB, t);
        }
    }

    float inv_l = 1.0f / l_run;
#pragma unroll
    for (int c = 0; c < 8; ++c)
#pragma unroll
        for (int r = 0; r < 4; ++r)
            outp[(size_t)(qw + col) * (NH * DH) + h * DH + 16 * c + 4 * g + r] = f2bf(acc[c][r] * inv_l);
}

// ---------------- launch ----------------
extern "C" void kernel_launch(void* const* d_in, const int* in_sizes, int n_in,
                              void* d_out, int out_size, void* d_ws, size_t ws_size,
                              hipStream_t stream) {
    const float* x         = (const float*)d_in[0];
    const float* W_kv_down = (const float*)d_in[2];
    const float* W_k_up    = (const float*)d_in[3];
    const float* W_v_up    = (const float*)d_in[4];
    const float* W_q_down  = (const float*)d_in[5];
    const float* W_q_up    = (const float*)d_in[6];
    const float* W_q_rope  = (const float*)d_in[7];
    const float* W_k_rope  = (const float*)d_in[8];
    const float* W_out     = (const float*)d_in[9];
    float* out = (float*)d_out;

    float* w = (float*)d_ws;
    float* cosT = w;
    float* sinT = w + (size_t)S * (DR / 2);
    u16* b = (u16*)(w + 2 * (size_t)S * (DR / 2));
    size_t off = 0;
    u16* x_bf    = b + off; off += (size_t)S * DM;
    u16* WT1     = b + off; off += (size_t)2560 * DM;
    u16* WT2     = b + off; off += (size_t)4096 * DKV;
    u16* WT3     = b + off; off += (size_t)3072 * DQ;
    u16* WT4     = b + off; off += (size_t)DM * DM;
    u16* down_kv = b + off; off += (size_t)S * DKV;
    u16* down_q  = b + off; off += (size_t)S * DQ;
    u16* q_asm   = b + off; off += (size_t)NH * S * DQK;
    u16* k_asm   = b + off; off += (size_t)NH * S * DQK;
    u16* vt      = b + off; off += (size_t)NH * DH * S;
    u16* attn_bf = b + off; off += (size_t)S * NH * DH;

    rope_table_kernel<<<(S * (DR / 2) + 255) / 256, 256, 0, stream>>>(cosT, sinT);

    convert_bf16_kernel<<<((S * DM / 4) + 255) / 256, 256, 0, stream>>>(x, x_bf, S * DM / 4);

    wt_all_kernel<<<3584, 256, 0, stream>>>(
        W_kv_down, W_q_down, W_k_rope, W_k_up, W_v_up, W_q_up, W_q_rope, W_out,
        WT1, WT1 + (size_t)512 * DM, WT1 + (size_t)1536 * DM,
        WT2, WT2 + (size_t)2048 * DKV,
        WT3, WT3 + (size_t)2048 * DQ, WT4);

    gemm_fused_kernel<0><<<dim3(2560 / 128, S / 64), 256, 0, stream>>>(
        x_bf, WT1, down_kv, down_q, k_asm, cosT, sinT, DM);
    gemm_fused_kernel<1><<<dim3(4096 / 128, S / 64), 256, 0, stream>>>(
        down_kv, WT2, k_asm, vt, nullptr, cosT, sinT, DKV);
    gemm_fused_kernel<2><<<dim3(3072 / 128, S / 64), 256, 0, stream>>>(
        down_q, WT3, q_asm, nullptr, nullptr, cosT, sinT, DQ);

    attn_mfma_kernel<<<512, 256, 0, stream>>>(q_asm, k_asm, vt, attn_bf);

    gemm_fused_kernel<3><<<dim3(DM / 128, S / 64), 256, 0, stream>>>(
        attn_bf, WT4, out, nullptr, nullptr, cosT, sinT, DM);
}

// Round 11
// 213.589 us; speedup vs baseline: 1.7409x; 1.7409x over previous
//
#include <hip/hip_runtime.h>
#include <hip/hip_bf16.h>
#include <math.h>

#define S 2048
#define DM 2048
#define NH 16
#define DH 128
#define DR 64
#define DKV 512
#define DQ 1024
#define DQK 192  // DH + DR
#define QSCALE 0.07216878364870323f  // 1/sqrt(192)

typedef __bf16 bf16x8 __attribute__((ext_vector_type(8)));
typedef float f32x4 __attribute__((ext_vector_type(4)));
typedef unsigned short u16;

__device__ inline unsigned int pack2_bf16(float a, float b) {
    __hip_bfloat16 ha = __float2bfloat16(a);
    __hip_bfloat16 hb = __float2bfloat16(b);
    unsigned short ua = *reinterpret_cast<unsigned short*>(&ha);
    unsigned short ub = *reinterpret_cast<unsigned short*>(&hb);
    return (unsigned int)ua | ((unsigned int)ub << 16);
}
__device__ inline u16 f2bf(float v) {
    __hip_bfloat16 hb = __float2bfloat16(v);
    return *reinterpret_cast<u16*>(&hb);
}
__device__ inline void gload_lds16(const void* g, void* l) {
    __builtin_amdgcn_global_load_lds(
        (const __attribute__((address_space(1))) void*)g,
        (__attribute__((address_space(3))) void*)l, 16, 0, 0);
}

// ---------------- fused preprocessing: RoPE table + x->bf16 + 8 weight transposes ----------------
// blocks [0,3584): weight transpose-convert; [3584,7680): x convert; [7680,7936): rope table
__global__ __launch_bounds__(256) void prep_kernel(
    const float* __restrict__ x,
    const float* __restrict__ W0, const float* __restrict__ W1, const float* __restrict__ W2,
    const float* __restrict__ W3, const float* __restrict__ W4, const float* __restrict__ W5,
    const float* __restrict__ W6, const float* __restrict__ W7,
    u16* __restrict__ x_bf,
    u16* __restrict__ D0, u16* __restrict__ D1, u16* __restrict__ D2, u16* __restrict__ D3,
    u16* __restrict__ D4, u16* __restrict__ D5, u16* __restrict__ D6, u16* __restrict__ D7,
    float* __restrict__ cosT, float* __restrict__ sinT) {
    __shared__ u16 tile[64][65];
    const int b = blockIdx.x;
    if (b < 3584) {
        const float* W; u16* D; int N, K, local;
        if (b < 256)       { W = W0; D = D0; N = 512;  K = 2048; local = b; }
        else if (b < 768)  { W = W1; D = D1; N = 1024; K = 2048; local = b - 256; }
        else if (b < 1280) { W = W2; D = D2; N = 1024; K = 2048; local = b - 768; }
        else if (b < 1536) { W = W3; D = D3; N = 2048; K = 512;  local = b - 1280; }
        else if (b < 1792) { W = W4; D = D4; N = 2048; K = 512;  local = b - 1536; }
        else if (b < 2304) { W = W5; D = D5; N = 2048; K = 1024; local = b - 1792; }
        else if (b < 2560) { W = W6; D = D6; N = 1024; K = 1024; local = b - 2304; }
        else               { W = W7; D = D7; N = 2048; K = 2048; local = b - 2560; }
        const int nt = N / 64;
        const int n0 = (local % nt) * 64;
        const int k0 = (local / nt) * 64;
        const int tx = threadIdx.x & 15;
        const int ty = threadIdx.x >> 4;
#pragma unroll
        for (int rep = 0; rep < 4; ++rep) {
            int kk = rep * 16 + ty;
            float4 v = *reinterpret_cast<const float4*>(&W[(size_t)(k0 + kk) * N + n0 + tx * 4]);
            tile[kk][tx * 4 + 0] = f2bf(v.x);
            tile[kk][tx * 4 + 1] = f2bf(v.y);
            tile[kk][tx * 4 + 2] = f2bf(v.z);
            tile[kk][tx * 4 + 3] = f2bf(v.w);
        }
        __syncthreads();
#pragma unroll
        for (int rep = 0; rep < 4; ++rep) {
            int nn = rep * 16 + ty;
            uint2 w;
            w.x = (unsigned int)tile[tx * 4 + 0][nn] | ((unsigned int)tile[tx * 4 + 1][nn] << 16);
            w.y = (unsigned int)tile[tx * 4 + 2][nn] | ((unsigned int)tile[tx * 4 + 3][nn] << 16);
            *reinterpret_cast<uint2*>(&D[(size_t)(n0 + nn) * K + k0 + tx * 4]) = w;
        }
    } else if (b < 7680) {
        int idx = (b - 3584) * 256 + threadIdx.x;  // n4 = S*DM/4 = 1048576 exactly
        float4 v = *reinterpret_cast<const float4*>(&x[(size_t)idx * 4]);
        uint2 w;
        w.x = pack2_bf16(v.x, v.y);
        w.y = pack2_bf16(v.z, v.w);
        *reinterpret_cast<uint2*>(&x_bf[(size_t)idx * 4]) = w;
    } else {
        int idx = (b - 7680) * 256 + threadIdx.x;  // S*(DR/2) = 65536 exactly
        int pos = idx / (DR / 2);
        int j   = idx % (DR / 2);
        float inv = __expf(-((float)(2 * j) / (float)DR) * logf(10000.0f));
        float ang = (float)pos * inv;
        cosT[idx] = cosf(ang);
        sinT[idx] = sinf(ang);
    }
}

// ---------------- bf16 MFMA GEMM core with fused epilogues (R8-verified structure) ----------------
// 64x128 tile, BK=32, 4 waves (2Mx2N), wave = 32x64 via 2x4 16x16x32 MFMAs.
// Conflict-free LDS slot map (consecutive-8-lane phase model), both-sides applied.
template <int MODE>
__device__ __forceinline__ void gemm_core(
    u16 (*lds)[6144],
    const u16* __restrict__ A, const u16* __restrict__ BT,
    void* __restrict__ P0v, void* __restrict__ P1v, void* __restrict__ P2v,
    const float* __restrict__ cosT, const float* __restrict__ sinT, int K,
    int bm, int bn) {
    const int tid  = threadIdx.x;
    const int wave = tid >> 6;
    const int lane = tid & 63;
    const int c16  = lane & 15;
    const int g    = lane >> 4;
    const int wm = (wave >> 1) * 32;
    const int wn = (wave & 1) * 64;

    f32x4 acc[2][4];
#pragma unroll
    for (int i = 0; i < 2; ++i)
#pragma unroll
        for (int j = 0; j < 4; ++j) acc[i][j] = f32x4{0.f, 0.f, 0.f, 0.f};

    auto stage = [&](int buf, int k0) {
        {
            int L = tid;
            int rp = L >> 3, e = L & 7, x = e ^ (rp & 7);
            int row = 2 * rp + (x >> 2), kc = x & 3;
            gload_lds16(A + (size_t)(bm + row) * K + k0 + kc * 8, &lds[buf][wave * 512]);
        }
#pragma unroll
        for (int r = 0; r < 2; ++r) {
            int L = r * 256 + tid;
            int rp = L >> 3, e = L & 7, x = e ^ (rp & 7);
            int row = 2 * rp + (x >> 2), kc = x & 3;
            gload_lds16(BT + (size_t)(bn + row) * K + k0 + kc * 8,
                        &lds[buf][2048 + (r * 256 + wave * 64) * 8]);
        }
    };

    const int NT = K / 32;
    stage(0, 0);
    __syncthreads();
    int cur = 0;
    for (int t = 0; t < NT; ++t) {
        if (t + 1 < NT) stage(cur ^ 1, (t + 1) * 32);
        bf16x8 af[2], bfr[4];
#pragma unroll
        for (int i = 0; i < 2; ++i) {
            int row  = wm + i * 16 + c16;
            int slot = ((row >> 1) << 3) + ((((row & 1) << 2) + g) ^ ((row >> 1) & 7));
            af[i] = *reinterpret_cast<const bf16x8*>(&lds[cur][slot * 8]);
        }
#pragma unroll
        for (int j = 0; j < 4; ++j) {
            int row  = wn + j * 16 + c16;
            int slot = ((row >> 1) << 3) + ((((row & 1) << 2) + g) ^ ((row >> 1) & 7));
            bfr[j] = *reinterpret_cast<const bf16x8*>(&lds[cur][2048 + slot * 8]);
        }
#pragma unroll
        for (int i = 0; i < 2; ++i)
#pragma unroll
            for (int j = 0; j < 4; ++j)
                acc[i][j] = __builtin_amdgcn_mfma_f32_16x16x32_bf16(af[i], bfr[j], acc[i][j], 0, 0, 0);
        __syncthreads();
        cur ^= 1;
    }

#pragma unroll
    for (int i = 0; i < 2; ++i)
#pragma unroll
        for (int j = 0; j < 4; ++j) {
            const int mrow = bm + wm + i * 16 + g * 4;
            const int col  = bn + wn + j * 16 + c16;
            if constexpr (MODE == 0) {
                if (col < 512) {
                    u16* down_kv = (u16*)P0v;
#pragma unroll
                    for (int r = 0; r < 4; ++r)
                        down_kv[(size_t)(mrow + r) * DKV + col] = f2bf(acc[i][j][r]);
                } else if (col < 1536) {
                    u16* down_q = (u16*)P1v;
#pragma unroll
                    for (int r = 0; r < 4; ++r)
                        down_q[(size_t)(mrow + r) * DQ + (col - 512)] = f2bf(acc[i][j][r]);
                } else {
                    u16* k_asm = (u16*)P2v;
                    const int cc = col - 1536, h = cc >> 6, rr = cc & 63, jj = rr >> 1;
#pragma unroll
                    for (int r = 0; r < 4; ++r) {
                        int pos = mrow + r;
                        float self = acc[i][j][r];
                        float vp   = __shfl_xor(self, 1);
                        float c = cosT[pos * (DR / 2) + jj];
                        float s = sinT[pos * (DR / 2) + jj];
                        float val = (rr & 1) ? (vp * s + self * c) : (self * c - vp * s);
                        k_asm[((size_t)h * S + pos) * DQK + DH + rr] = f2bf(val);
                    }
                }
            } else if constexpr (MODE == 1) {
                if (col < 2048) {
                    u16* k_asm = (u16*)P0v;
                    const int h = col >> 7, d = col & 127;
#pragma unroll
                    for (int r = 0; r < 4; ++r)
                        k_asm[((size_t)h * S + mrow + r) * DQK + d] = f2bf(acc[i][j][r]);
                } else {
                    u16* vt = (u16*)P1v;
                    const int cc = col - 2048, h = cc >> 7, d = cc & 127;
                    uint2 w;
                    w.x = pack2_bf16(acc[i][j][0], acc[i][j][1]);
                    w.y = pack2_bf16(acc[i][j][2], acc[i][j][3]);
                    *reinterpret_cast<uint2*>(&vt[((size_t)h * DH + d) * S + mrow]) = w;
                }
            } else if constexpr (MODE == 2) {
                u16* q_asm = (u16*)P0v;
                if (col < 2048) {
                    const int h = col >> 7, d = col & 127;
#pragma unroll
                    for (int r = 0; r < 4; ++r)
                        q_asm[((size_t)h * S + mrow + r) * DQK + d] = f2bf(acc[i][j][r] * QSCALE);
                } else {
                    const int cc = col - 2048, h = cc >> 6, rr = cc & 63, jj = rr >> 1;
#pragma unroll
                    for (int r = 0; r < 4; ++r) {
                        int pos = mrow + r;
                        float self = acc[i][j][r];
                        float vp   = __shfl_xor(self, 1);
                        float c = cosT[pos * (DR / 2) + jj];
                        float s = sinT[pos * (DR / 2) + jj];
                        float val = (rr & 1) ? (vp * s + self * c) : (self * c - vp * s);
                        q_asm[((size_t)h * S + pos) * DQK + DH + rr] = f2bf(val * QSCALE);
                    }
                }
            } else {  // MODE 3
                float* outp = (float*)P0v;
#pragma unroll
                for (int r = 0; r < 4; ++r)
                    outp[(size_t)(mrow + r) * DM + col] = acc[i][j][r];
            }
        }
}

template <int MODE>
__global__ __launch_bounds__(256) void gemm_fused_kernel(
    const u16* __restrict__ A, const u16* __restrict__ BT,
    void* __restrict__ P0v, void* __restrict__ P1v, void* __restrict__ P2v,
    const float* __restrict__ cosT, const float* __restrict__ sinT, int K) {
    __shared__ u16 lds[2][6144];
    gemm_core<MODE>(lds, A, BT, P0v, P1v, P2v, cosT, sinT, K,
                    blockIdx.y * 64, blockIdx.x * 128);
}

// G2 (1024 blocks) + G3 (768 blocks) merged: independent GEMMs, tails overlap.
__global__ __launch_bounds__(256) void gemm_g23_kernel(
    const u16* __restrict__ down_kv, const u16* __restrict__ WT2,
    const u16* __restrict__ down_q,  const u16* __restrict__ WT3,
    u16* __restrict__ k_asm, u16* __restrict__ vt, u16* __restrict__ q_asm,
    const float* __restrict__ cosT, const float* __restrict__ sinT) {
    __shared__ u16 lds[2][6144];
    const int b = blockIdx.x;
    if (b < 1024) {  // G2: N=4096 (32 n-tiles), K=512
        gemm_core<1>(lds, down_kv, WT2, k_asm, vt, nullptr, cosT, sinT, DKV,
                     (b >> 5) * 64, (b & 31) * 128);
    } else {         // G3: N=3072 (24 n-tiles), K=1024
        const int l = b - 1024;
        gemm_core<2>(lds, down_q, WT3, q_asm, nullptr, nullptr, cosT, sinT, DQ,
                     (l / 24) * 64, (l % 24) * 128);
    }
}

// ---------------- MFMA flash attention (R6-verified, 86us) ----------------
// 4 waves/block, QBLK=64, KV tiles of 32 double-buffered via global_load_lds.
// Conflict-free slot maps (consecutive-8-lane phase model), both-sides applied.
__global__ __launch_bounds__(256) void attn_mfma_kernel(const u16* __restrict__ q,   // (NH,S,192) pre-scaled
                                                        const u16* __restrict__ k,   // (NH,S,192)
                                                        const u16* __restrict__ vt,  // (NH,DH,S)
                                                        u16* __restrict__ outp) {    // (S, NH*DH) bf16
    const int wgid = blockIdx.x;
    const int xcd  = wgid & 7;
    const int i    = wgid >> 3;  // 0..63 per xcd
    const int h  = (i < 32) ? (xcd * 2) : (xcd * 2 + 1);
    const int qt = (i < 32) ? (31 - i) : (i - 32);
    const int q0 = qt * 64;

    const int tid  = threadIdx.x;
    const int wave = tid >> 6;
    const int lane = tid & 63;
    const int col  = lane & 15;
    const int g    = lane >> 4;
    const int qw   = q0 + wave * 16;

    __shared__ u16 Kt[2][32 * DQK];              // slot(row,ch)=row*24+8*(ch>>3)+((ch&7)^(row&7))
    __shared__ u16 Vt[2][DH * 32];               // slot(d,kc)=(d>>1)*8+((4*(d&1)+kc)^((d>>1)&7))
    __shared__ __align__(16) u16 p_lds[4][512];  // per-wave P, same slot form as Vt (row=q)

    const int r7  = col & 7;          // K row-class
    const int pv7 = (col >> 1) & 7;   // V/P row-pair class
    const int pvb = (col & 1) << 2;

    // Q fragments: lane holds Q[qw+col][g*8+e + 32c]
    bf16x8 qf[6];
    const u16* qbase = q + ((size_t)h * S + qw + col) * DQK + g * 8;
#pragma unroll
    for (int c = 0; c < 6; ++c) qf[c] = *reinterpret_cast<const bf16x8*>(qbase + c * 32);

    f32x4 acc[8];
#pragma unroll
    for (int c = 0; c < 8; ++c) acc[c] = f32x4{0.f, 0.f, 0.f, 0.f};
    float m_run = -1e30f, l_run = 0.f;

    auto stage = [&](int buf, int j0) {
        // K: 768 chunks; inverse: row=L/24, rem=L%24, ch=8*(rem>>3)+((rem&7)^(row&7))
#pragma unroll
        for (int r = 0; r < 3; ++r) {
            int L   = r * 256 + tid;
            int row = L / 24, rem = L - row * 24;
            int ch  = ((rem >> 3) << 3) + ((rem & 7) ^ (row & 7));
            gload_lds16(k + ((size_t)h * S + j0 + row) * DQK + ch * 8,
                        &Kt[buf][(r * 256 + wave * 64) * 8]);
        }
        // V: 512 chunks; inverse: rp=L>>3, x=(L&7)^(rp&7), d=2rp+(x>>2), kc=x&3
#pragma unroll
        for (int r = 0; r < 2; ++r) {
            int L  = r * 256 + tid;
            int rp = L >> 3, x = (L & 7) ^ (rp & 7);
            int d  = 2 * rp + (x >> 2), kc = x & 3;
            gload_lds16(vt + ((size_t)h * DH + d) * S + j0 + kc * 8,
                        &Vt[buf][(r * 256 + wave * 64) * 8]);
        }
    };

    const int kend = q0 + 64;
    stage(0, 0);
    __syncthreads();
    int cur = 0;
    for (int j0 = 0; j0 < kend; j0 += 32) {
        if (j0 + 32 < kend) stage(cur ^ 1, j0 + 32);
        // ---- QK^T from Kt[cur]
        f32x4 st[2];
        st[0] = f32x4{0.f, 0.f, 0.f, 0.f};
        st[1] = f32x4{0.f, 0.f, 0.f, 0.f};
#pragma unroll
        for (int t = 0; t < 2; ++t) {
            int rb = (16 * t + col) * 24;
#pragma unroll
            for (int c = 0; c < 6; ++c) {
                int ch   = g + 4 * c;
                int slot = rb + ((ch >> 3) << 3) + ((ch & 7) ^ r7);
                bf16x8 kf = *reinterpret_cast<const bf16x8*>(&Kt[cur][slot * 8]);
                st[t] = __builtin_amdgcn_mfma_f32_16x16x32_bf16(kf, qf[c], st[t], 0, 0, 0);
            }
        }
        // ---- causal mask (q = qw+col, key = j0+16t+4g+r)
#pragma unroll
        for (int t = 0; t < 2; ++t) {
            if (j0 + 16 * t + 15 > qw) {
#pragma unroll
                for (int r = 0; r < 4; ++r) {
                    int key = j0 + 16 * t + 4 * g + r;
                    st[t][r] = (key > qw + col) ? -1e30f : st[t][r];
                }
            }
        }
        // ---- online softmax with defer-max
        float tmax = fmaxf(fmaxf(fmaxf(st[0][0], st[0][1]), fmaxf(st[0][2], st[0][3])),
                           fmaxf(fmaxf(st[1][0], st[1][1]), fmaxf(st[1][2], st[1][3])));
        tmax = fmaxf(tmax, __shfl_xor(tmax, 16));
        tmax = fmaxf(tmax, __shfl_xor(tmax, 32));
        float m_new;
        if (__all(tmax - m_run <= 8.0f)) {
            m_new = m_run;  // defer: P bounded by e^8, no rescale
        } else {
            m_new = fmaxf(m_run, tmax);
            float r_scale = __expf(m_run - m_new);
            l_run *= r_scale;
#pragma unroll
            for (int c = 0; c < 8; ++c) {
                acc[c][0] *= r_scale; acc[c][1] *= r_scale;
                acc[c][2] *= r_scale; acc[c][3] *= r_scale;
            }
            m_run = m_new;
        }
        float p[8];
        float psum = 0.f;
#pragma unroll
        for (int t = 0; t < 2; ++t)
#pragma unroll
            for (int r = 0; r < 4; ++r) {
                float pv = __expf(st[t][r] - m_new);
                p[t * 4 + r] = pv;
                psum += pv;
            }
        psum += __shfl_xor(psum, 16);
        psum += __shfl_xor(psum, 32);
        l_run += psum;
        // ---- P -> p_lds (wave-private; chunk = 2t+(g>>1), half = g&1)
#pragma unroll
        for (int t = 0; t < 2; ++t) {
            uint2 w;
            w.x = pack2_bf16(p[t * 4 + 0], p[t * 4 + 1]);
            w.y = pack2_bf16(p[t * 4 + 2], p[t * 4 + 3]);
            int ch   = 2 * t + (g >> 1);
            int slot = ((col >> 1) << 3) + ((pvb + ch) ^ pv7);
            *reinterpret_cast<uint2*>(&p_lds[wave][slot * 8 + (g & 1) * 4]) = w;
        }
        {
            int slot = ((col >> 1) << 3) + ((pvb + g) ^ pv7);
            bf16x8 pf = *reinterpret_cast<const bf16x8*>(&p_lds[wave][slot * 8]);
            // ---- PV from Vt[cur]
#pragma unroll
            for (int c = 0; c < 8; ++c) {
                int d  = 16 * c + col;
                int vs = ((d >> 1) << 3) + ((pvb + g) ^ pv7);
                bf16x8 vf = *reinterpret_cast<const bf16x8*>(&Vt[cur][vs * 8]);
                acc[c] = __builtin_amdgcn_mfma_f32_16x16x32_bf16(vf, pf, acc[c], 0, 0, 0);
            }
        }
        __syncthreads();  // all reads of cur done + staged cur^1 drained
        cur ^= 1;
    }

    float inv_l = 1.0f / l_run;
#pragma unroll
    for (int c = 0; c < 8; ++c)
#pragma unroll
        for (int r = 0; r < 4; ++r)
            outp[(size_t)(qw + col) * (NH * DH) + h * DH + 16 * c + 4 * g + r] = f2bf(acc[c][r] * inv_l);
}

// ---------------- launch ----------------
extern "C" void kernel_launch(void* const* d_in, const int* in_sizes, int n_in,
                              void* d_out, int out_size, void* d_ws, size_t ws_size,
                              hipStream_t stream) {
    const float* x         = (const float*)d_in[0];
    const float* W_kv_down = (const float*)d_in[2];
    const float* W_k_up    = (const float*)d_in[3];
    const float* W_v_up    = (const float*)d_in[4];
    const float* W_q_down  = (const float*)d_in[5];
    const float* W_q_up    = (const float*)d_in[6];
    const float* W_q_rope  = (const float*)d_in[7];
    const float* W_k_rope  = (const float*)d_in[8];
    const float* W_out     = (const float*)d_in[9];
    float* out = (float*)d_out;

    float* w = (float*)d_ws;
    float* cosT = w;
    float* sinT = w + (size_t)S * (DR / 2);
    u16* b = (u16*)(w + 2 * (size_t)S * (DR / 2));
    size_t off = 0;
    u16* x_bf    = b + off; off += (size_t)S * DM;
    u16* WT1     = b + off; off += (size_t)2560 * DM;
    u16* WT2     = b + off; off += (size_t)4096 * DKV;
    u16* WT3     = b + off; off += (size_t)3072 * DQ;
    u16* WT4     = b + off; off += (size_t)DM * DM;
    u16* down_kv = b + off; off += (size_t)S * DKV;
    u16* down_q  = b + off; off += (size_t)S * DQ;
    u16* q_asm   = b + off; off += (size_t)NH * S * DQK;
    u16* k_asm   = b + off; off += (size_t)NH * S * DQK;
    u16* vt      = b + off; off += (size_t)NH * DH * S;
    u16* attn_bf = b + off; off += (size_t)S * NH * DH;

    // fused preprocessing: weights transpose (3584) + x convert (4096) + rope table (256)
    prep_kernel<<<7936, 256, 0, stream>>>(
        x, W_kv_down, W_q_down, W_k_rope, W_k_up, W_v_up, W_q_up, W_q_rope, W_out,
        x_bf,
        WT1, WT1 + (size_t)512 * DM, WT1 + (size_t)1536 * DM,
        WT2, WT2 + (size_t)2048 * DKV,
        WT3, WT3 + (size_t)2048 * DQ, WT4,
        cosT, sinT);

    // G1: x @ [W_kv_down | W_q_down | W_k_rope], N=2560, K=2048
    gemm_fused_kernel<0><<<dim3(2560 / 128, S / 64), 256, 0, stream>>>(
        x_bf, WT1, down_kv, down_q, k_asm, cosT, sinT, DM);

    // G2+G3 merged (independent given G1): 1024 + 768 = 1792 blocks
    gemm_g23_kernel<<<1792, 256, 0, stream>>>(
        down_kv, WT2, down_q, WT3, k_asm, vt, q_asm, cosT, sinT);

    attn_mfma_kernel<<<512, 256, 0, stream>>>(q_asm, k_asm, vt, attn_bf);

    // G4: attn_out @ W_out, N=2048, K=2048 -> fp32 d_out
    gemm_fused_kernel<3><<<dim3(DM / 128, S / 64), 256, 0, stream>>>(
        attn_bf, WT4, out, nullptr, nullptr, cosT, sinT, DM);
}